// Round 9
// baseline (674.647 us; speedup 1.0000x reference)
//
#include <hip/hip_runtime.h>
#include <stdint.h>

// RecursiveLSTM: B=1024 sequences, T=96, H=50, num_pred=12.
// WAVE-PER-SEQUENCE (1024 blocks x 64 threads). Lane j<50 owns hidden unit
// j. ROUND-9: h broadcast via v_readlane (register-file, zero latency)
// instead of LDS -- round-8 counters showed ~500 cyc/step of exposed
// latency (LDS write->read turnaround + lgkmcnt stalls) at 1 wave/SIMD
// where nothing can hide it. v_pk_fma_f32 is half-rate on gfx950 (FP32
// spec 157 TF = 256 FLOP/cy/CU), so scalar v_fmac_f32 with an SGPR
// h-broadcast costs the same 400 cyc FMA floor and needs no packed h.
// Weights stay in hand-managed fixed regs v[40:239] (round-8 win: the RA
// otherwise parks them in AGPRs and pays a v_accvgpr_read per use).
// t-loop: 4 head fma + 50x{readlane + 4 fmac} + activation tail; only
// memory op is the x ds_read_b32, prefetched one full body ahead (2x
// unroll). 3-SGPR rotation (s21-s23) refilled 3 groups ahead.

#define HSZ   50
#define TLEN  96
#define MAXP  16

// one k-group: 4 fmac consuming SGPR h_k + refill the SGPR with h_{k+3}
#define KG(SR,WI,WF,WG,WO,KN) \
    "v_fmac_f32 v8,  " SR ", v" WI "\n\t" \
    "v_fmac_f32 v10, " SR ", v" WF "\n\t" \
    "v_fmac_f32 v12, " SR ", v" WG "\n\t" \
    "v_fmac_f32 v14, " SR ", v" WO "\n\t" \
    "v_readlane_b32 " SR ", v31, " KN "\n\t"
// last three groups: no refill
#define KGN(SR,WI,WF,WG,WO) \
    "v_fmac_f32 v8,  " SR ", v" WI "\n\t" \
    "v_fmac_f32 v10, " SR ", v" WF "\n\t" \
    "v_fmac_f32 v12, " SR ", v" WG "\n\t" \
    "v_fmac_f32 v14, " SR ", v" WO "\n\t"

#define KALL \
    KG("s21","40","90","140","190","3")    KG("s22","41","91","141","191","4")   \
    KG("s23","42","92","142","192","5")    KG("s21","43","93","143","193","6")   \
    KG("s22","44","94","144","194","7")    KG("s23","45","95","145","195","8")   \
    KG("s21","46","96","146","196","9")    KG("s22","47","97","147","197","10")  \
    KG("s23","48","98","148","198","11")   KG("s21","49","99","149","199","12")  \
    KG("s22","50","100","150","200","13")  KG("s23","51","101","151","201","14") \
    KG("s21","52","102","152","202","15")  KG("s22","53","103","153","203","16") \
    KG("s23","54","104","154","204","17")  KG("s21","55","105","155","205","18") \
    KG("s22","56","106","156","206","19")  KG("s23","57","107","157","207","20") \
    KG("s21","58","108","158","208","21")  KG("s22","59","109","159","209","22") \
    KG("s23","60","110","160","210","23")  KG("s21","61","111","161","211","24") \
    KG("s22","62","112","162","212","25")  KG("s23","63","113","163","213","26") \
    KG("s21","64","114","164","214","27")  KG("s22","65","115","165","215","28") \
    KG("s23","66","116","166","216","29")  KG("s21","67","117","167","217","30") \
    KG("s22","68","118","168","218","31")  KG("s23","69","119","169","219","32") \
    KG("s21","70","120","170","220","33")  KG("s22","71","121","171","221","34") \
    KG("s23","72","122","172","222","35")  KG("s21","73","123","173","223","36") \
    KG("s22","74","124","174","224","37")  KG("s23","75","125","175","225","38") \
    KG("s21","76","126","176","226","39")  KG("s22","77","127","177","227","40") \
    KG("s23","78","128","178","228","41")  KG("s21","79","129","179","229","42") \
    KG("s22","80","130","180","230","43")  KG("s23","81","131","181","231","44") \
    KG("s21","82","132","182","232","45")  KG("s22","83","133","183","233","46") \
    KG("s23","84","134","184","234","47")  KG("s21","85","135","185","235","48") \
    KG("s22","86","136","186","236","49")                                        \
    KGN("s23","87","137","187","237")      KGN("s21","88","138","188","238")     \
    KGN("s22","89","139","189","239")

// activation tail: sigmoid(i,f,o), tanh(g), c/h update (exp2-based, rcp)
#define TAIL \
    "v_mul_f32 v20, 0xbfb8aa3b, v8\n\t"  \
    "v_mul_f32 v21, 0xbfb8aa3b, v10\n\t" \
    "v_mul_f32 v22, 0x4038aa3b, v12\n\t" \
    "v_mul_f32 v23, 0xbfb8aa3b, v14\n\t" \
    "v_exp_f32 v20, v20\n\t"             \
    "v_exp_f32 v21, v21\n\t"             \
    "v_exp_f32 v22, v22\n\t"             \
    "v_exp_f32 v23, v23\n\t"             \
    "v_add_f32 v20, 1.0, v20\n\t"        \
    "v_add_f32 v21, 1.0, v21\n\t"        \
    "v_add_f32 v22, 1.0, v22\n\t"        \
    "v_add_f32 v23, 1.0, v23\n\t"        \
    "v_rcp_f32 v20, v20\n\t"             \
    "v_rcp_f32 v21, v21\n\t"             \
    "v_rcp_f32 v22, v22\n\t"             \
    "v_rcp_f32 v23, v23\n\t"             \
    "s_nop 1\n\t"                        \
    "v_fma_f32 v22, -2.0, v22, 1.0\n\t"  \
    "v_mul_f32 v24, v20, v22\n\t"        \
    "v_fma_f32 v30, v21, v30, v24\n\t"   \
    "v_mul_f32 v25, 0x4038aa3b, v30\n\t" \
    "v_exp_f32 v25, v25\n\t"             \
    "s_nop 1\n\t"                        \
    "v_add_f32 v25, 1.0, v25\n\t"        \
    "v_rcp_f32 v25, v25\n\t"             \
    "s_nop 1\n\t"                        \
    "v_fma_f32 v25, -2.0, v25, 1.0\n\t"  \
    "v_mul_f32 v31, v23, v25\n\t"

// one LSTM step: prologue readlanes, head (x contribution), 50 k-groups, tail
#define BODY(XV) \
    "v_readlane_b32 s21, v31, 0\n\t"            \
    "v_readlane_b32 s22, v31, 1\n\t"            \
    "v_readlane_b32 s23, v31, 2\n\t"            \
    "v_fma_f32 v8,  %[xwi], " XV ", %[bi]\n\t"  \
    "v_fma_f32 v10, %[xwf], " XV ", %[bf]\n\t"  \
    "v_fma_f32 v12, %[xwg], " XV ", %[bg]\n\t"  \
    "v_fma_f32 v14, %[xwo], " XV ", %[bo]\n\t"  \
    KALL                                        \
    TAIL

__global__ __attribute__((amdgpu_flat_work_group_size(64, 64),
                          amdgpu_waves_per_eu(1, 1)))
void rec_lstm_kernel(const float* __restrict__ x,
                     const float* __restrict__ W_ih,
                     const float* __restrict__ W_hh,
                     const float* __restrict__ b_ih,
                     const float* __restrict__ b_hh,
                     const float* __restrict__ W_fc,
                     const float* __restrict__ b_fc,
                     const int*   __restrict__ num_pred,
                     float*       __restrict__ out)
{
    const int b = blockIdx.x;
    const int j = threadIdx.x;            // hidden-unit index; active j<50
    const int u = (j < HSZ) ? j : 0;      // clamped row for idle lanes

    __shared__ float xbuf[TLEN + MAXP];   // x ++ appended preds (only LDS)

    const uint32_t xbuf_off = (uint32_t)(uintptr_t)&xbuf[0];

    // per-gate-row byte offsets into W_hh (rows u, u+50, u+100, u+150)
    const uint32_t woi = (uint32_t)(u      ) * 200u;
    const uint32_t wof = (uint32_t)(u +  50) * 200u;
    const uint32_t wog = (uint32_t)(u + 100) * 200u;
    const uint32_t woo = (uint32_t)(u + 150) * 200u;

    const float xii = W_ih[u], xif = W_ih[u+50], xig = W_ih[u+100], xio = W_ih[u+150];
    const float bi = b_ih[u]     + b_hh[u];
    const float bf = b_ih[u+50]  + b_hh[u+50];
    const float bg = b_ih[u+100] + b_hh[u+100];
    const float bo = b_ih[u+150] + b_hh[u+150];
    const float wfc = (j < HSZ) ? W_fc[j] : 0.f;
    const float bfc = b_fc[0];
    const int   NP  = num_pred[0];

    if (j < 48) { xbuf[j] = x[b*TLEN + j]; xbuf[j+48] = x[b*TLEN + j + 48]; }
    __syncthreads();

    for (int p = 0; p < NP; ++p) {
        float hn;
        const uint32_t xa0 = xbuf_off + 4u * (uint32_t)p;

        asm volatile(
            // ---- pass prologue: x addr, xv(t=0) prefetch, c=h=0 ----
            "v_mov_b32 v32, %[xa0]\n\t"
            "ds_read_b32 v28, v32\n\t"
            "v_mov_b32 v30, 0\n\t"                 // c = 0
            "v_mov_b32 v31, 0\n\t"                 // h = 0
            // ---- W_hh rows -> fixed regs (i:40-89 f:90-139 g:140-189 o:190-239)
            "global_load_dwordx4 v[40:43],  %[woi], %[wb]\n\t"
            "global_load_dwordx4 v[44:47],  %[woi], %[wb] offset:16\n\t"
            "global_load_dwordx4 v[48:51],  %[woi], %[wb] offset:32\n\t"
            "global_load_dwordx4 v[52:55],  %[woi], %[wb] offset:48\n\t"
            "global_load_dwordx4 v[56:59],  %[woi], %[wb] offset:64\n\t"
            "global_load_dwordx4 v[60:63],  %[woi], %[wb] offset:80\n\t"
            "global_load_dwordx4 v[64:67],  %[woi], %[wb] offset:96\n\t"
            "global_load_dwordx4 v[68:71],  %[woi], %[wb] offset:112\n\t"
            "global_load_dwordx4 v[72:75],  %[woi], %[wb] offset:128\n\t"
            "global_load_dwordx4 v[76:79],  %[woi], %[wb] offset:144\n\t"
            "global_load_dwordx4 v[80:83],  %[woi], %[wb] offset:160\n\t"
            "global_load_dwordx4 v[84:87],  %[woi], %[wb] offset:176\n\t"
            "global_load_dwordx2 v[88:89],  %[woi], %[wb] offset:192\n\t"
            "global_load_dwordx4 v[90:93],  %[wof], %[wb]\n\t"
            "global_load_dwordx4 v[94:97],  %[wof], %[wb] offset:16\n\t"
            "global_load_dwordx4 v[98:101], %[wof], %[wb] offset:32\n\t"
            "global_load_dwordx4 v[102:105],%[wof], %[wb] offset:48\n\t"
            "global_load_dwordx4 v[106:109],%[wof], %[wb] offset:64\n\t"
            "global_load_dwordx4 v[110:113],%[wof], %[wb] offset:80\n\t"
            "global_load_dwordx4 v[114:117],%[wof], %[wb] offset:96\n\t"
            "global_load_dwordx4 v[118:121],%[wof], %[wb] offset:112\n\t"
            "global_load_dwordx4 v[122:125],%[wof], %[wb] offset:128\n\t"
            "global_load_dwordx4 v[126:129],%[wof], %[wb] offset:144\n\t"
            "global_load_dwordx4 v[130:133],%[wof], %[wb] offset:160\n\t"
            "global_load_dwordx4 v[134:137],%[wof], %[wb] offset:176\n\t"
            "global_load_dwordx2 v[138:139],%[wof], %[wb] offset:192\n\t"
            "global_load_dwordx4 v[140:143],%[wog], %[wb]\n\t"
            "global_load_dwordx4 v[144:147],%[wog], %[wb] offset:16\n\t"
            "global_load_dwordx4 v[148:151],%[wog], %[wb] offset:32\n\t"
            "global_load_dwordx4 v[152:155],%[wog], %[wb] offset:48\n\t"
            "global_load_dwordx4 v[156:159],%[wog], %[wb] offset:64\n\t"
            "global_load_dwordx4 v[160:163],%[wog], %[wb] offset:80\n\t"
            "global_load_dwordx4 v[164:167],%[wog], %[wb] offset:96\n\t"
            "global_load_dwordx4 v[168:171],%[wog], %[wb] offset:112\n\t"
            "global_load_dwordx4 v[172:175],%[wog], %[wb] offset:128\n\t"
            "global_load_dwordx4 v[176:179],%[wog], %[wb] offset:144\n\t"
            "global_load_dwordx4 v[180:183],%[wog], %[wb] offset:160\n\t"
            "global_load_dwordx4 v[184:187],%[wog], %[wb] offset:176\n\t"
            "global_load_dwordx2 v[188:189],%[wog], %[wb] offset:192\n\t"
            "global_load_dwordx4 v[190:193],%[woo], %[wb]\n\t"
            "global_load_dwordx4 v[194:197],%[woo], %[wb] offset:16\n\t"
            "global_load_dwordx4 v[198:201],%[woo], %[wb] offset:32\n\t"
            "global_load_dwordx4 v[202:205],%[woo], %[wb] offset:48\n\t"
            "global_load_dwordx4 v[206:209],%[woo], %[wb] offset:64\n\t"
            "global_load_dwordx4 v[210:213],%[woo], %[wb] offset:80\n\t"
            "global_load_dwordx4 v[214:217],%[woo], %[wb] offset:96\n\t"
            "global_load_dwordx4 v[218:221],%[woo], %[wb] offset:112\n\t"
            "global_load_dwordx4 v[222:225],%[woo], %[wb] offset:128\n\t"
            "global_load_dwordx4 v[226:229],%[woo], %[wb] offset:144\n\t"
            "global_load_dwordx4 v[230:233],%[woo], %[wb] offset:160\n\t"
            "global_load_dwordx4 v[234:237],%[woo], %[wb] offset:176\n\t"
            "global_load_dwordx2 v[238:239],%[woo], %[wb] offset:192\n\t"
            "s_waitcnt vmcnt(0) lgkmcnt(0)\n\t"
            "s_mov_b32 s20, 48\n\t"               // 48 double-steps = 96
            // ================= t-loop (2x unrolled) =================
            "2:\n\t"
            "ds_read_b32 v29, v32 offset:4\n\t"   // xv for t+1
            "s_waitcnt lgkmcnt(1)\n\t"            // xv(t) = v28 ready
            BODY("v28")
            "ds_read_b32 v28, v32 offset:8\n\t"   // xv for t+2
            "v_add_u32 v32, 8, v32\n\t"
            "s_waitcnt lgkmcnt(1)\n\t"            // xv(t+1) = v29 ready
            BODY("v29")
            "s_sub_u32 s20, s20, 1\n\t"
            "s_cmp_lg_u32 s20, 0\n\t"
            "s_cbranch_scc1 2b\n\t"
            "v_mov_b32 %[hn], v31\n\t"
            : [hn] "=v"(hn)
            : [wb] "s"(W_hh),
              [woi] "v"(woi), [wof] "v"(wof), [wog] "v"(wog), [woo] "v"(woo),
              [xwi] "v"(xii), [xwf] "v"(xif), [xwg] "v"(xig), [xwo] "v"(xio),
              [bi] "v"(bi), [bf] "v"(bf), [bg] "v"(bg), [bo] "v"(bo),
              [xa0] "v"(xa0)
            : "memory", "scc", "s20", "s21", "s22", "s23",
              "v8","v10","v12","v14","v20","v21","v22","v23","v24","v25",
              "v28","v29","v30","v31","v32",
              "v40","v41","v42","v43","v44","v45","v46","v47","v48","v49",
              "v50","v51","v52","v53","v54","v55","v56","v57","v58","v59",
              "v60","v61","v62","v63","v64","v65","v66","v67","v68","v69",
              "v70","v71","v72","v73","v74","v75","v76","v77","v78","v79",
              "v80","v81","v82","v83","v84","v85","v86","v87","v88","v89",
              "v90","v91","v92","v93","v94","v95","v96","v97","v98","v99",
              "v100","v101","v102","v103","v104","v105","v106","v107","v108","v109",
              "v110","v111","v112","v113","v114","v115","v116","v117","v118","v119",
              "v120","v121","v122","v123","v124","v125","v126","v127","v128","v129",
              "v130","v131","v132","v133","v134","v135","v136","v137","v138","v139",
              "v140","v141","v142","v143","v144","v145","v146","v147","v148","v149",
              "v150","v151","v152","v153","v154","v155","v156","v157","v158","v159",
              "v160","v161","v162","v163","v164","v165","v166","v167","v168","v169",
              "v170","v171","v172","v173","v174","v175","v176","v177","v178","v179",
              "v180","v181","v182","v183","v184","v185","v186","v187","v188","v189",
              "v190","v191","v192","v193","v194","v195","v196","v197","v198","v199",
              "v200","v201","v202","v203","v204","v205","v206","v207","v208","v209",
              "v210","v211","v212","v213","v214","v215","v216","v217","v218","v219",
              "v220","v221","v222","v223","v224","v225","v226","v227","v228","v229",
              "v230","v231","v232","v233","v234","v235","v236","v237","v238","v239");

        // ---- FC head: pred = h . W_fc + b_fc (full-wave shuffle reduce) ----
        float v = (j < HSZ) ? hn * wfc : 0.f;
        #pragma unroll
        for (int off = 32; off >= 1; off >>= 1)
            v += __shfl_down(v, off, 64);
        if (j == 0) {
            const float pr = v + bfc;
            xbuf[TLEN + p] = pr;               // becomes next input
            out[b * NP + p] = pr;
        }
        __syncthreads();   // xbuf write visible before next pass reads it
    }
}

extern "C" void kernel_launch(void* const* d_in, const int* in_sizes, int n_in,
                              void* d_out, int out_size, void* d_ws, size_t ws_size,
                              hipStream_t stream)
{
    const float* x    = (const float*)d_in[0];
    const float* W_ih = (const float*)d_in[1];
    const float* W_hh = (const float*)d_in[2];
    const float* b_ih = (const float*)d_in[3];
    const float* b_hh = (const float*)d_in[4];
    const float* W_fc = (const float*)d_in[5];
    const float* b_fc = (const float*)d_in[6];
    const int*   np   = (const int*)d_in[7];
    float* out = (float*)d_out;

    const int B = in_sizes[0] / TLEN;   // 1024
    rec_lstm_kernel<<<B, 64, 0, stream>>>(x, W_ih, W_hh, b_ih, b_hh,
                                          W_fc, b_fc, np, out);
}

// Round 11
// 494.604 us; speedup vs baseline: 1.3640x; 1.3640x over previous
//
#include <hip/hip_runtime.h>
#include <stdint.h>

// RecursiveLSTM: B=1024 sequences, T=96, H=50, num_pred=12.
// WAVE-PER-SEQUENCE (1024 blocks x 64 threads), weights in FIXED regs
// v[56:255] (r8 win). ROUND-11 = ROUND-10 RERUN (r10 was an infra failure:
// "container failed twice", no compile error; r6->r7 precedent showed this
// resolves on unmodified rerun).
// DUAL-PASS LOCKSTEP: passes (p, p+1) run interleaved in one wave for
// t=0..94 (two independent dep chains hide each other's LDS turnaround +
// trans latency; r8 was 42% idle on one chain), then serialized epilogue:
// A step95 -> FC(swizzle butterfly) -> pred[p] -> B step95 (xv = pred
// in-register) -> FC -> pred[p+1]. One ds_read2_b32 feeds both passes.
// pk_fma broadcast via same-address ds_read_b128 (r9: readlane/SGPR
// broadcast ~2x more issue-expensive than LDS broadcast).

#define HSZ   50
#define TLEN  96
#define MAXP  16

// ---- 8 pk_fma group macros (A accs v26-33, B accs v34-41) ----
#define GA(WT,WI0,WF0,WG0,WO0,H0,WI1,WF1,WG1,WO1,H1,POST) \
    "s_waitcnt lgkmcnt(" WT ")\n\t" \
    "v_pk_fma_f32 v[26:27], v[" WI0 "], v[" H0 "], v[26:27]\n\t" \
    "v_pk_fma_f32 v[28:29], v[" WF0 "], v[" H0 "], v[28:29]\n\t" \
    "v_pk_fma_f32 v[30:31], v[" WG0 "], v[" H0 "], v[30:31]\n\t" \
    "v_pk_fma_f32 v[32:33], v[" WO0 "], v[" H0 "], v[32:33]\n\t" \
    "v_pk_fma_f32 v[26:27], v[" WI1 "], v[" H1 "], v[26:27]\n\t" \
    "v_pk_fma_f32 v[28:29], v[" WF1 "], v[" H1 "], v[28:29]\n\t" \
    "v_pk_fma_f32 v[30:31], v[" WG1 "], v[" H1 "], v[30:31]\n\t" \
    "v_pk_fma_f32 v[32:33], v[" WO1 "], v[" H1 "], v[32:33]\n\t" \
    POST
#define GB(WT,WI0,WF0,WG0,WO0,H0,WI1,WF1,WG1,WO1,H1,POST) \
    "s_waitcnt lgkmcnt(" WT ")\n\t" \
    "v_pk_fma_f32 v[34:35], v[" WI0 "], v[" H0 "], v[34:35]\n\t" \
    "v_pk_fma_f32 v[36:37], v[" WF0 "], v[" H0 "], v[36:37]\n\t" \
    "v_pk_fma_f32 v[38:39], v[" WG0 "], v[" H0 "], v[38:39]\n\t" \
    "v_pk_fma_f32 v[40:41], v[" WO0 "], v[" H0 "], v[40:41]\n\t" \
    "v_pk_fma_f32 v[34:35], v[" WI1 "], v[" H1 "], v[34:35]\n\t" \
    "v_pk_fma_f32 v[36:37], v[" WF1 "], v[" H1 "], v[36:37]\n\t" \
    "v_pk_fma_f32 v[38:39], v[" WG1 "], v[" H1 "], v[38:39]\n\t" \
    "v_pk_fma_f32 v[40:41], v[" WO1 "], v[" H1 "], v[40:41]\n\t" \
    POST

#define AM0(WT,H0,H1,POST)  GA(WT,"56:57","106:107","156:157","206:207",H0,"58:59","108:109","158:159","208:209",H1,POST)
#define AM1(WT,H0,H1,POST)  GA(WT,"60:61","110:111","160:161","210:211",H0,"62:63","112:113","162:163","212:213",H1,POST)
#define AM2(WT,H0,H1,POST)  GA(WT,"64:65","114:115","164:165","214:215",H0,"66:67","116:117","166:167","216:217",H1,POST)
#define AM3(WT,H0,H1,POST)  GA(WT,"68:69","118:119","168:169","218:219",H0,"70:71","120:121","170:171","220:221",H1,POST)
#define AM4(WT,H0,H1,POST)  GA(WT,"72:73","122:123","172:173","222:223",H0,"74:75","124:125","174:175","224:225",H1,POST)
#define AM5(WT,H0,H1,POST)  GA(WT,"76:77","126:127","176:177","226:227",H0,"78:79","128:129","178:179","228:229",H1,POST)
#define AM6(WT,H0,H1,POST)  GA(WT,"80:81","130:131","180:181","230:231",H0,"82:83","132:133","182:183","232:233",H1,POST)
#define AM7(WT,H0,H1,POST)  GA(WT,"84:85","134:135","184:185","234:235",H0,"86:87","136:137","186:187","236:237",H1,POST)
#define AM8(WT,H0,H1,POST)  GA(WT,"88:89","138:139","188:189","238:239",H0,"90:91","140:141","190:191","240:241",H1,POST)
#define AM9(WT,H0,H1,POST)  GA(WT,"92:93","142:143","192:193","242:243",H0,"94:95","144:145","194:195","244:245",H1,POST)
#define AM10(WT,H0,H1,POST) GA(WT,"96:97","146:147","196:197","246:247",H0,"98:99","148:149","198:199","248:249",H1,POST)
#define AM11(WT,H0,H1,POST) GA(WT,"100:101","150:151","200:201","250:251",H0,"102:103","152:153","202:203","252:253",H1,POST)
#define BM0(WT,H0,H1,POST)  GB(WT,"56:57","106:107","156:157","206:207",H0,"58:59","108:109","158:159","208:209",H1,POST)
#define BM1(WT,H0,H1,POST)  GB(WT,"60:61","110:111","160:161","210:211",H0,"62:63","112:113","162:163","212:213",H1,POST)
#define BM2(WT,H0,H1,POST)  GB(WT,"64:65","114:115","164:165","214:215",H0,"66:67","116:117","166:167","216:217",H1,POST)
#define BM3(WT,H0,H1,POST)  GB(WT,"68:69","118:119","168:169","218:219",H0,"70:71","120:121","170:171","220:221",H1,POST)
#define BM4(WT,H0,H1,POST)  GB(WT,"72:73","122:123","172:173","222:223",H0,"74:75","124:125","174:175","224:225",H1,POST)
#define BM5(WT,H0,H1,POST)  GB(WT,"76:77","126:127","176:177","226:227",H0,"78:79","128:129","178:179","228:229",H1,POST)
#define BM6(WT,H0,H1,POST)  GB(WT,"80:81","130:131","180:181","230:231",H0,"82:83","132:133","182:183","232:233",H1,POST)
#define BM7(WT,H0,H1,POST)  GB(WT,"84:85","134:135","184:185","234:235",H0,"86:87","136:137","186:187","236:237",H1,POST)
#define BM8(WT,H0,H1,POST)  GB(WT,"88:89","138:139","188:189","238:239",H0,"90:91","140:141","190:191","240:241",H1,POST)
#define BM9(WT,H0,H1,POST)  GB(WT,"92:93","142:143","192:193","242:243",H0,"94:95","144:145","194:195","244:245",H1,POST)
#define BM10(WT,H0,H1,POST) GB(WT,"96:97","146:147","196:197","246:247",H0,"98:99","148:149","198:199","248:249",H1,POST)
#define BM11(WT,H0,H1,POST) GB(WT,"100:101","150:151","200:201","250:251",H0,"102:103","152:153","202:203","252:253",H1,POST)
#define GA12(WT,H) \
    "s_waitcnt lgkmcnt(" WT ")\n\t" \
    "v_pk_fma_f32 v[26:27], v[104:105], v[" H "], v[26:27]\n\t" \
    "v_pk_fma_f32 v[28:29], v[154:155], v[" H "], v[28:29]\n\t" \
    "v_pk_fma_f32 v[30:31], v[204:205], v[" H "], v[30:31]\n\t" \
    "v_pk_fma_f32 v[32:33], v[254:255], v[" H "], v[32:33]\n\t"
#define GB12(WT,H) \
    "s_waitcnt lgkmcnt(" WT ")\n\t" \
    "v_pk_fma_f32 v[34:35], v[104:105], v[" H "], v[34:35]\n\t" \
    "v_pk_fma_f32 v[36:37], v[154:155], v[" H "], v[36:37]\n\t" \
    "v_pk_fma_f32 v[38:39], v[204:205], v[" H "], v[38:39]\n\t" \
    "v_pk_fma_f32 v[40:41], v[254:255], v[" H "], v[40:41]\n\t"

#define HEAD_A(XV) \
    "v_fma_f32 v26, %[xwi], " XV ", %[bi]\n\t"  "v_mov_b32 v27, 0\n\t" \
    "v_fma_f32 v28, %[xwf], " XV ", %[bf]\n\t"  "v_mov_b32 v29, 0\n\t" \
    "v_fma_f32 v30, %[xwg], " XV ", %[bg]\n\t"  "v_mov_b32 v31, 0\n\t" \
    "v_fma_f32 v32, %[xwo], " XV ", %[bo]\n\t"  "v_mov_b32 v33, 0\n\t"
#define HEAD_B(XV) \
    "v_fma_f32 v34, %[xwi], " XV ", %[bi]\n\t"  "v_mov_b32 v35, 0\n\t" \
    "v_fma_f32 v36, %[xwf], " XV ", %[bf]\n\t"  "v_mov_b32 v37, 0\n\t" \
    "v_fma_f32 v38, %[xwg], " XV ", %[bg]\n\t"  "v_mov_b32 v39, 0\n\t" \
    "v_fma_f32 v40, %[xwo], " XV ", %[bo]\n\t"  "v_mov_b32 v41, 0\n\t"

#define FOLD_A \
    "v_add_f32 v26, v26, v27\n\t" "v_add_f32 v28, v28, v29\n\t" \
    "v_add_f32 v30, v30, v31\n\t" "v_add_f32 v32, v32, v33\n\t"
#define FOLD_B \
    "v_add_f32 v34, v34, v35\n\t" "v_add_f32 v36, v36, v37\n\t" \
    "v_add_f32 v38, v38, v39\n\t" "v_add_f32 v40, v40, v41\n\t"

// dual tail: A(ai v26,af v28,ag v30,ao v32,c v52,hn v54) B(+8, c v53, hn v55)
#define DTAIL \
    "v_mul_f32 v27, 0xbfb8aa3b, v26\n\t" "v_mul_f32 v35, 0xbfb8aa3b, v34\n\t" \
    "v_mul_f32 v29, 0xbfb8aa3b, v28\n\t" "v_mul_f32 v37, 0xbfb8aa3b, v36\n\t" \
    "v_mul_f32 v31, 0x4038aa3b, v30\n\t" "v_mul_f32 v39, 0x4038aa3b, v38\n\t" \
    "v_mul_f32 v33, 0xbfb8aa3b, v32\n\t" "v_mul_f32 v41, 0xbfb8aa3b, v40\n\t" \
    "v_exp_f32 v27, v27\n\t" "v_exp_f32 v35, v35\n\t" \
    "v_exp_f32 v29, v29\n\t" "v_exp_f32 v37, v37\n\t" \
    "v_exp_f32 v31, v31\n\t" "v_exp_f32 v39, v39\n\t" \
    "v_exp_f32 v33, v33\n\t" "v_exp_f32 v41, v41\n\t" \
    "v_add_f32 v27, 1.0, v27\n\t" "v_add_f32 v35, 1.0, v35\n\t" \
    "v_add_f32 v29, 1.0, v29\n\t" "v_add_f32 v37, 1.0, v37\n\t" \
    "v_add_f32 v31, 1.0, v31\n\t" "v_add_f32 v39, 1.0, v39\n\t" \
    "v_add_f32 v33, 1.0, v33\n\t" "v_add_f32 v41, 1.0, v41\n\t" \
    "v_rcp_f32 v27, v27\n\t" "v_rcp_f32 v35, v35\n\t" \
    "v_rcp_f32 v29, v29\n\t" "v_rcp_f32 v37, v37\n\t" \
    "v_rcp_f32 v31, v31\n\t" "v_rcp_f32 v39, v39\n\t" \
    "v_rcp_f32 v33, v33\n\t" "v_rcp_f32 v41, v41\n\t" \
    "v_fma_f32 v31, -2.0, v31, 1.0\n\t" "v_fma_f32 v39, -2.0, v39, 1.0\n\t" \
    "v_mul_f32 v26, v27, v31\n\t"       "v_mul_f32 v34, v35, v39\n\t" \
    "v_fma_f32 v52, v29, v52, v26\n\t"  "v_fma_f32 v53, v37, v53, v34\n\t" \
    "v_mul_f32 v28, 0x4038aa3b, v52\n\t" "v_mul_f32 v36, 0x4038aa3b, v53\n\t" \
    "v_exp_f32 v28, v28\n\t" "v_exp_f32 v36, v36\n\t" \
    "s_nop 0\n\t" \
    "v_add_f32 v28, 1.0, v28\n\t" "v_add_f32 v36, 1.0, v36\n\t" \
    "v_rcp_f32 v28, v28\n\t" "v_rcp_f32 v36, v36\n\t" \
    "s_nop 0\n\t" \
    "v_fma_f32 v28, -2.0, v28, 1.0\n\t" "v_fma_f32 v36, -2.0, v36, 1.0\n\t" \
    "v_mul_f32 v54, v33, v28\n\t" "v_mul_f32 v55, v41, v36\n\t"

// single-pass tails for the epilogue steps
#define STAIL_A \
    "v_mul_f32 v27, 0xbfb8aa3b, v26\n\t" "v_mul_f32 v29, 0xbfb8aa3b, v28\n\t" \
    "v_mul_f32 v31, 0x4038aa3b, v30\n\t" "v_mul_f32 v33, 0xbfb8aa3b, v32\n\t" \
    "v_exp_f32 v27, v27\n\t" "v_exp_f32 v29, v29\n\t" \
    "v_exp_f32 v31, v31\n\t" "v_exp_f32 v33, v33\n\t" \
    "v_add_f32 v27, 1.0, v27\n\t" "v_add_f32 v29, 1.0, v29\n\t" \
    "v_add_f32 v31, 1.0, v31\n\t" "v_add_f32 v33, 1.0, v33\n\t" \
    "v_rcp_f32 v27, v27\n\t" "v_rcp_f32 v29, v29\n\t" \
    "v_rcp_f32 v31, v31\n\t" "v_rcp_f32 v33, v33\n\t" \
    "s_nop 1\n\t" \
    "v_fma_f32 v31, -2.0, v31, 1.0\n\t" \
    "v_mul_f32 v26, v27, v31\n\t" \
    "v_fma_f32 v52, v29, v52, v26\n\t" \
    "v_mul_f32 v28, 0x4038aa3b, v52\n\t" \
    "v_exp_f32 v28, v28\n\t" \
    "s_nop 1\n\t" \
    "v_add_f32 v28, 1.0, v28\n\t" \
    "v_rcp_f32 v28, v28\n\t" \
    "s_nop 1\n\t" \
    "v_fma_f32 v28, -2.0, v28, 1.0\n\t" \
    "v_mul_f32 v54, v33, v28\n\t"
#define STAIL_B \
    "v_mul_f32 v35, 0xbfb8aa3b, v34\n\t" "v_mul_f32 v37, 0xbfb8aa3b, v36\n\t" \
    "v_mul_f32 v39, 0x4038aa3b, v38\n\t" "v_mul_f32 v41, 0xbfb8aa3b, v40\n\t" \
    "v_exp_f32 v35, v35\n\t" "v_exp_f32 v37, v37\n\t" \
    "v_exp_f32 v39, v39\n\t" "v_exp_f32 v41, v41\n\t" \
    "v_add_f32 v35, 1.0, v35\n\t" "v_add_f32 v37, 1.0, v37\n\t" \
    "v_add_f32 v39, 1.0, v39\n\t" "v_add_f32 v41, 1.0, v41\n\t" \
    "v_rcp_f32 v35, v35\n\t" "v_rcp_f32 v37, v37\n\t" \
    "v_rcp_f32 v39, v39\n\t" "v_rcp_f32 v41, v41\n\t" \
    "s_nop 1\n\t" \
    "v_fma_f32 v39, -2.0, v39, 1.0\n\t" \
    "v_mul_f32 v34, v35, v39\n\t" \
    "v_fma_f32 v53, v37, v53, v34\n\t" \
    "v_mul_f32 v36, 0x4038aa3b, v53\n\t" \
    "v_exp_f32 v36, v36\n\t" \
    "s_nop 1\n\t" \
    "v_add_f32 v36, 1.0, v36\n\t" \
    "v_rcp_f32 v36, v36\n\t" \
    "s_nop 1\n\t" \
    "v_fma_f32 v36, -2.0, v36, 1.0\n\t" \
    "v_mul_f32 v55, v41, v36\n\t"

// FC head: sum over lanes of HN*wfc + bfc -> pred in v27 (all lanes);
// store to xbuf at %[xa0]+PADD.
#define FC(HN,PADD) \
    "v_mul_f32 v26, " HN ", %[wfc]\n\t" \
    "s_nop 1\n\t" \
    "ds_swizzle_b32 v27, v26 offset:0x041F\n\t" \
    "s_waitcnt lgkmcnt(0)\n\t" \
    "v_add_f32 v26, v26, v27\n\t" \
    "ds_swizzle_b32 v27, v26 offset:0x081F\n\t" \
    "s_waitcnt lgkmcnt(0)\n\t" \
    "v_add_f32 v26, v26, v27\n\t" \
    "ds_swizzle_b32 v27, v26 offset:0x101F\n\t" \
    "s_waitcnt lgkmcnt(0)\n\t" \
    "v_add_f32 v26, v26, v27\n\t" \
    "ds_swizzle_b32 v27, v26 offset:0x201F\n\t" \
    "s_waitcnt lgkmcnt(0)\n\t" \
    "v_add_f32 v26, v26, v27\n\t" \
    "ds_swizzle_b32 v27, v26 offset:0x401F\n\t" \
    "s_waitcnt lgkmcnt(0)\n\t" \
    "v_add_f32 v26, v26, v27\n\t" \
    "s_nop 1\n\t" \
    "v_readlane_b32 s24, v26, 0\n\t" \
    "v_readlane_b32 s25, v26, 32\n\t" \
    "s_nop 4\n\t" \
    "v_mov_b32 v27, s24\n\t" \
    "v_add_f32 v27, s25, v27\n\t" \
    "v_add_f32 v27, %[bfc], v27\n\t" \
    "v_add_u32 v28, " PADD ", %[xa0]\n\t" \
    "ds_write_b32 v28, v27\n\t"

__global__ __attribute__((amdgpu_flat_work_group_size(64, 64),
                          amdgpu_waves_per_eu(1, 1)))
void rec_lstm_kernel(const float* __restrict__ x,
                     const float* __restrict__ W_ih,
                     const float* __restrict__ W_hh,
                     const float* __restrict__ b_ih,
                     const float* __restrict__ b_hh,
                     const float* __restrict__ W_fc,
                     const float* __restrict__ b_fc,
                     const int*   __restrict__ num_pred,
                     float*       __restrict__ out)
{
    const int b = blockIdx.x;
    const int j = threadIdx.x;            // hidden-unit index; active j<50
    const int u = (j < HSZ) ? j : 0;      // clamped row for idle lanes

    __shared__ float xbuf[TLEN + MAXP];   // x ++ appended preds
    __shared__ __align__(16) float hAB[128];  // hA = [0:64), hB = [64:128)

    const uint32_t xbuf_off = (uint32_t)(uintptr_t)&xbuf[0];
    const uint32_t hab      = (uint32_t)(uintptr_t)&hAB[0];
    const uint32_t haw      = hab + 4u * (uint32_t)j;
    const uint32_t woi      = (uint32_t)u * 200u;   // byte offset of i-row

    const float xii = W_ih[u], xif = W_ih[u+50], xig = W_ih[u+100], xio = W_ih[u+150];
    const float bi = b_ih[u]     + b_hh[u];
    const float bf = b_ih[u+50]  + b_hh[u+50];
    const float bg = b_ih[u+100] + b_hh[u+100];
    const float bo = b_ih[u+150] + b_hh[u+150];
    const float wfc = (j < HSZ) ? W_fc[j] : 0.f;
    const float bfc = b_fc[0];
    const int   NP  = num_pred[0];

    if (j < 48) { xbuf[j] = x[b*TLEN + j]; xbuf[j+48] = x[b*TLEN + j + 48]; }

    #pragma unroll 1
    for (int pp = 0; pp < NP; pp += 2) {
        uint32_t xaddr = xbuf_off + 4u * (uint32_t)pp;

        asm volatile(
            // ---- derive f/g/o row offsets; load weights v[56:255] ----
            "s_mov_b32 s24, 10000\n\t"
            "v_add_u32 v0, s24, %[woi]\n\t"
            "s_mov_b32 s24, 20000\n\t"
            "v_add_u32 v4, s24, %[woi]\n\t"
            "s_mov_b32 s24, 30000\n\t"
            "v_add_u32 v44, s24, %[woi]\n\t"
            "global_load_dwordx4 v[56:59],  %[woi], %[wb]\n\t"
            "global_load_dwordx4 v[60:63],  %[woi], %[wb] offset:16\n\t"
            "global_load_dwordx4 v[64:67],  %[woi], %[wb] offset:32\n\t"
            "global_load_dwordx4 v[68:71],  %[woi], %[wb] offset:48\n\t"
            "global_load_dwordx4 v[72:75],  %[woi], %[wb] offset:64\n\t"
            "global_load_dwordx4 v[76:79],  %[woi], %[wb] offset:80\n\t"
            "global_load_dwordx4 v[80:83],  %[woi], %[wb] offset:96\n\t"
            "global_load_dwordx4 v[84:87],  %[woi], %[wb] offset:112\n\t"
            "global_load_dwordx4 v[88:91],  %[woi], %[wb] offset:128\n\t"
            "global_load_dwordx4 v[92:95],  %[woi], %[wb] offset:144\n\t"
            "global_load_dwordx4 v[96:99],  %[woi], %[wb] offset:160\n\t"
            "global_load_dwordx4 v[100:103],%[woi], %[wb] offset:176\n\t"
            "global_load_dwordx2 v[104:105],%[woi], %[wb] offset:192\n\t"
            "global_load_dwordx4 v[106:109], v0, %[wb]\n\t"
            "global_load_dwordx4 v[110:113], v0, %[wb] offset:16\n\t"
            "global_load_dwordx4 v[114:117], v0, %[wb] offset:32\n\t"
            "global_load_dwordx4 v[118:121], v0, %[wb] offset:48\n\t"
            "global_load_dwordx4 v[122:125], v0, %[wb] offset:64\n\t"
            "global_load_dwordx4 v[126:129], v0, %[wb] offset:80\n\t"
            "global_load_dwordx4 v[130:133], v0, %[wb] offset:96\n\t"
            "global_load_dwordx4 v[134:137], v0, %[wb] offset:112\n\t"
            "global_load_dwordx4 v[138:141], v0, %[wb] offset:128\n\t"
            "global_load_dwordx4 v[142:145], v0, %[wb] offset:144\n\t"
            "global_load_dwordx4 v[146:149], v0, %[wb] offset:160\n\t"
            "global_load_dwordx4 v[150:153], v0, %[wb] offset:176\n\t"
            "global_load_dwordx2 v[154:155], v0, %[wb] offset:192\n\t"
            "global_load_dwordx4 v[156:159], v4, %[wb]\n\t"
            "global_load_dwordx4 v[160:163], v4, %[wb] offset:16\n\t"
            "global_load_dwordx4 v[164:167], v4, %[wb] offset:32\n\t"
            "global_load_dwordx4 v[168:171], v4, %[wb] offset:48\n\t"
            "global_load_dwordx4 v[172:175], v4, %[wb] offset:64\n\t"
            "global_load_dwordx4 v[176:179], v4, %[wb] offset:80\n\t"
            "global_load_dwordx4 v[180:183], v4, %[wb] offset:96\n\t"
            "global_load_dwordx4 v[184:187], v4, %[wb] offset:112\n\t"
            "global_load_dwordx4 v[188:191], v4, %[wb] offset:128\n\t"
            "global_load_dwordx4 v[192:195], v4, %[wb] offset:144\n\t"
            "global_load_dwordx4 v[196:199], v4, %[wb] offset:160\n\t"
            "global_load_dwordx4 v[200:203], v4, %[wb] offset:176\n\t"
            "global_load_dwordx2 v[204:205], v4, %[wb] offset:192\n\t"
            "global_load_dwordx4 v[206:209], v44, %[wb]\n\t"
            "global_load_dwordx4 v[210:213], v44, %[wb] offset:16\n\t"
            "global_load_dwordx4 v[214:217], v44, %[wb] offset:32\n\t"
            "global_load_dwordx4 v[218:221], v44, %[wb] offset:48\n\t"
            "global_load_dwordx4 v[222:225], v44, %[wb] offset:64\n\t"
            "global_load_dwordx4 v[226:229], v44, %[wb] offset:80\n\t"
            "global_load_dwordx4 v[230:233], v44, %[wb] offset:96\n\t"
            "global_load_dwordx4 v[234:237], v44, %[wb] offset:112\n\t"
            "global_load_dwordx4 v[238:241], v44, %[wb] offset:128\n\t"
            "global_load_dwordx4 v[242:245], v44, %[wb] offset:144\n\t"
            "global_load_dwordx4 v[246:249], v44, %[wb] offset:160\n\t"
            "global_load_dwordx4 v[250:253], v44, %[wb] offset:176\n\t"
            "global_load_dwordx2 v[254:255], v44, %[wb] offset:192\n\t"
            // ---- zero c/h, prefetch xv pair for m=0 ----
            "v_mov_b32 v52, 0\n\t"             // c_A
            "v_mov_b32 v53, 0\n\t"             // c_B
            "v_mov_b32 v54, 0\n\t"
            "ds_write_b32 %[hAw], v54\n\t"               // h_A[j] = 0
            "ds_write_b32 %[hAw], v54 offset:256\n\t"    // h_B[j] = 0
            "ds_read2_b32 v[42:43], %[xa0] offset0:0 offset1:1\n\t"
            "s_waitcnt vmcnt(0)\n\t"
            "s_mov_b32 s20, 95\n\t"
            // ================= dual t-loop: steps 0..94 =================
            "2:\n\t"
            "ds_read_b128 v[0:3],   %[hAb]\n\t"
            "ds_read_b128 v[44:47], %[hAb] offset:256\n\t"
            "ds_read_b128 v[4:7],   %[hAb] offset:16\n\t"
            "ds_read_b128 v[48:51], %[hAb] offset:272\n\t"
            "s_waitcnt lgkmcnt(4)\n\t"       // xv pair (and h writes) done
            HEAD_A("v42")
            HEAD_B("v43")
            "v_add_u32 %[xa0], 4, %[xa0]\n\t"
            "ds_read2_b32 v[42:43], %[xa0] offset0:0 offset1:1\n\t"
            AM0("4","0:1","2:3",   "ds_read_b128 v[0:3], %[hAb] offset:32\n\t")
            BM0("4","44:45","46:47","ds_read_b128 v[44:47], %[hAb] offset:288\n\t")
            AM1("4","4:5","6:7",   "ds_read_b128 v[4:7], %[hAb] offset:48\n\t")
            BM1("4","48:49","50:51","ds_read_b128 v[48:51], %[hAb] offset:304\n\t")
            AM2("3","0:1","2:3",   "ds_read_b128 v[0:3], %[hAb] offset:64\n\t")
            BM2("3","44:45","46:47","ds_read_b128 v[44:47], %[hAb] offset:320\n\t")
            AM3("3","4:5","6:7",   "ds_read_b128 v[4:7], %[hAb] offset:80\n\t")
            BM3("3","48:49","50:51","ds_read_b128 v[48:51], %[hAb] offset:336\n\t")
            AM4("3","0:1","2:3",   "ds_read_b128 v[0:3], %[hAb] offset:96\n\t")
            BM4("3","44:45","46:47","ds_read_b128 v[44:47], %[hAb] offset:352\n\t")
            AM5("3","4:5","6:7",   "ds_read_b128 v[4:7], %[hAb] offset:112\n\t")
            BM5("3","48:49","50:51","ds_read_b128 v[48:51], %[hAb] offset:368\n\t")
            AM6("3","0:1","2:3",   "ds_read_b128 v[0:3], %[hAb] offset:128\n\t")
            BM6("3","44:45","46:47","ds_read_b128 v[44:47], %[hAb] offset:384\n\t")
            AM7("3","4:5","6:7",   "ds_read_b128 v[4:7], %[hAb] offset:144\n\t")
            BM7("3","48:49","50:51","ds_read_b128 v[48:51], %[hAb] offset:400\n\t")
            AM8("3","0:1","2:3",   "ds_read_b128 v[0:3], %[hAb] offset:160\n\t")
            BM8("3","44:45","46:47","ds_read_b128 v[44:47], %[hAb] offset:416\n\t")
            AM9("3","4:5","6:7",   "ds_read_b128 v[4:7], %[hAb] offset:176\n\t")
            BM9("3","48:49","50:51","ds_read_b128 v[48:51], %[hAb] offset:432\n\t")
            AM10("3","0:1","2:3",  "ds_read_b128 v[0:3], %[hAb] offset:192\n\t")
            BM10("3","44:45","46:47","ds_read_b128 v[44:47], %[hAb] offset:448\n\t")
            AM11("3","4:5","6:7","")
            BM11("2","48:49","50:51","")
            GA12("1","0:1")
            GB12("0","44:45")
            FOLD_A
            FOLD_B
            DTAIL
            "ds_write_b32 %[hAw], v54\n\t"
            "ds_write_b32 %[hAw], v55 offset:256\n\t"
            "s_sub_u32 s20, s20, 1\n\t"
            "s_cmp_lg_u32 s20, 0\n\t"
            "s_cbranch_scc1 2b\n\t"
            // ================= epilogue: A step 95 =================
            "ds_read_b128 v[0:3],   %[hAb]\n\t"
            "ds_read_b128 v[4:7],   %[hAb] offset:16\n\t"
            "ds_read_b128 v[44:47], %[hAb] offset:32\n\t"
            "ds_read_b128 v[48:51], %[hAb] offset:48\n\t"
            HEAD_A("v42")
            AM0("3","0:1","2:3",    "ds_read_b128 v[0:3], %[hAb] offset:64\n\t")
            AM1("3","4:5","6:7",    "ds_read_b128 v[4:7], %[hAb] offset:80\n\t")
            AM2("3","44:45","46:47","ds_read_b128 v[44:47], %[hAb] offset:96\n\t")
            AM3("3","48:49","50:51","ds_read_b128 v[48:51], %[hAb] offset:112\n\t")
            AM4("3","0:1","2:3",    "ds_read_b128 v[0:3], %[hAb] offset:128\n\t")
            AM5("3","4:5","6:7",    "ds_read_b128 v[4:7], %[hAb] offset:144\n\t")
            AM6("3","44:45","46:47","ds_read_b128 v[44:47], %[hAb] offset:160\n\t")
            AM7("3","48:49","50:51","ds_read_b128 v[48:51], %[hAb] offset:176\n\t")
            AM8("3","0:1","2:3",    "ds_read_b128 v[0:3], %[hAb] offset:192\n\t")
            AM9("3","4:5","6:7","")
            AM10("2","44:45","46:47","")
            AM11("1","48:49","50:51","")
            GA12("0","0:1")
            FOLD_A
            STAIL_A
            FC("v54","4")                          // pred[p] -> v27, xbuf[96+p]
            // ================= epilogue: B step 95 (xv = v27) =============
            "ds_read_b128 v[0:3],   %[hAb] offset:256\n\t"
            "ds_read_b128 v[4:7],   %[hAb] offset:272\n\t"
            "ds_read_b128 v[44:47], %[hAb] offset:288\n\t"
            "ds_read_b128 v[48:51], %[hAb] offset:304\n\t"
            HEAD_B("v27")
            BM0("3","0:1","2:3",    "ds_read_b128 v[0:3], %[hAb] offset:320\n\t")
            BM1("3","4:5","6:7",    "ds_read_b128 v[4:7], %[hAb] offset:336\n\t")
            BM2("3","44:45","46:47","ds_read_b128 v[44:47], %[hAb] offset:352\n\t")
            BM3("3","48:49","50:51","ds_read_b128 v[48:51], %[hAb] offset:368\n\t")
            BM4("3","0:1","2:3",    "ds_read_b128 v[0:3], %[hAb] offset:384\n\t")
            BM5("3","4:5","6:7",    "ds_read_b128 v[4:7], %[hAb] offset:400\n\t")
            BM6("3","44:45","46:47","ds_read_b128 v[44:47], %[hAb] offset:416\n\t")
            BM7("3","48:49","50:51","ds_read_b128 v[48:51], %[hAb] offset:432\n\t")
            BM8("3","0:1","2:3",    "ds_read_b128 v[0:3], %[hAb] offset:448\n\t")
            BM9("3","4:5","6:7","")
            BM10("2","44:45","46:47","")
            BM11("1","48:49","50:51","")
            GB12("0","0:1")
            FOLD_B
            STAIL_B
            FC("v55","8")                          // pred[p+1] -> xbuf[97+p]
            "s_waitcnt lgkmcnt(0)\n\t"
            : [xa0] "+v"(xaddr)
            : [wb] "s"(W_hh), [woi] "v"(woi),
              [xwi] "v"(xii), [xwf] "v"(xif), [xwg] "v"(xig), [xwo] "v"(xio),
              [bi] "v"(bi), [bf] "v"(bf), [bg] "v"(bg), [bo] "v"(bo),
              [wfc] "v"(wfc), [bfc] "v"(bfc),
              [hAb] "v"(hab), [hAw] "v"(haw)
            : "memory", "scc", "s20", "s24", "s25",
              "v0","v1","v2","v3","v4","v5","v6","v7",
              "v26","v27","v28","v29","v30","v31","v32","v33","v34","v35",
              "v36","v37","v38","v39","v40","v41","v42","v43","v44","v45",
              "v46","v47","v48","v49","v50","v51","v52","v53","v54","v55",
              "v56","v57","v58","v59","v60","v61","v62","v63","v64","v65",
              "v66","v67","v68","v69","v70","v71","v72","v73","v74","v75",
              "v76","v77","v78","v79","v80","v81","v82","v83","v84","v85",
              "v86","v87","v88","v89","v90","v91","v92","v93","v94","v95",
              "v96","v97","v98","v99","v100","v101","v102","v103","v104","v105",
              "v106","v107","v108","v109","v110","v111","v112","v113","v114","v115",
              "v116","v117","v118","v119","v120","v121","v122","v123","v124","v125",
              "v126","v127","v128","v129","v130","v131","v132","v133","v134","v135",
              "v136","v137","v138","v139","v140","v141","v142","v143","v144","v145",
              "v146","v147","v148","v149","v150","v151","v152","v153","v154","v155",
              "v156","v157","v158","v159","v160","v161","v162","v163","v164","v165",
              "v166","v167","v168","v169","v170","v171","v172","v173","v174","v175",
              "v176","v177","v178","v179","v180","v181","v182","v183","v184","v185",
              "v186","v187","v188","v189","v190","v191","v192","v193","v194","v195",
              "v196","v197","v198","v199","v200","v201","v202","v203","v204","v205",
              "v206","v207","v208","v209","v210","v211","v212","v213","v214","v215",
              "v216","v217","v218","v219","v220","v221","v222","v223","v224","v225",
              "v226","v227","v228","v229","v230","v231","v232","v233","v234","v235",
              "v236","v237","v238","v239","v240","v241","v242","v243","v244","v245",
              "v246","v247","v248","v249","v250","v251","v252","v253","v254","v255");
    }

    // out written once from LDS (preds were stored to xbuf[96+p] in-asm)
    if (j < NP) out[b * NP + j] = xbuf[TLEN + j];
}

extern "C" void kernel_launch(void* const* d_in, const int* in_sizes, int n_in,
                              void* d_out, int out_size, void* d_ws, size_t ws_size,
                              hipStream_t stream)
{
    const float* x    = (const float*)d_in[0];
    const float* W_ih = (const float*)d_in[1];
    const float* W_hh = (const float*)d_in[2];
    const float* b_ih = (const float*)d_in[3];
    const float* b_hh = (const float*)d_in[4];
    const float* W_fc = (const float*)d_in[5];
    const float* b_fc = (const float*)d_in[6];
    const int*   np   = (const int*)d_in[7];
    float* out = (float*)d_out;

    const int B = in_sizes[0] / TLEN;   // 1024
    rec_lstm_kernel<<<B, 64, 0, stream>>>(x, W_ih, W_hh, b_ih, b_hh,
                                          W_fc, b_fc, np, out);
}